// Round 9
// baseline (625.332 us; speedup 1.0000x reference)
//
#include <hip/hip_runtime.h>
#include <math.h>

// Problem constants (from reference)
#define BATCH 1024
#define DIM   512            // K; also fp8 row bytes
#define NCLS  100000
#define SCALE_S 64.0f
#define MARGIN  0.5f
#define EPS_REF 1e-7f
#define SEXP 92.332482616893656878f   // S * log2(e): acc = S*log2e*wf -> exp2(acc)

// Fused-GEMM tiling (32x32x16 fp8 MFMA)
#define NSLAB 64             // classes (N) per block = 2 strips of 32
#define NBLK  1563           // ceil(NCLS/NSLAB)
#define CHUNK 32             // batch rows per compute chunk
#define NCHUNK_WAVE 8        // 1024 rows / (32 rows * 4 waves)
#define NRSCOPY 8            // rowsum replicas (atomic line-contention /8)

typedef __attribute__((ext_vector_type(16))) float floatx16;
typedef __attribute__((ext_vector_type(2)))  long  longx2;

#if __has_builtin(__builtin_amdgcn_exp2f)
#define EXP2(x) __builtin_amdgcn_exp2f(x)
#else
#define EXP2(x) exp2f(x)
#endif

// sum within each 16-lane group — pure VALU via DPP (harness-proven in R8).
__device__ __forceinline__ float red16(float v) {
    int x;
    x = __builtin_amdgcn_update_dpp(0, __builtin_bit_cast(int, v), 0x128, 0xf, 0xf, true);
    v += __builtin_bit_cast(float, x);
    x = __builtin_amdgcn_update_dpp(0, __builtin_bit_cast(int, v), 0x124, 0xf, 0xf, true);
    v += __builtin_bit_cast(float, x);
    x = __builtin_amdgcn_update_dpp(0, __builtin_bit_cast(int, v), 0x4E, 0xf, 0xf, true);
    v += __builtin_bit_cast(float, x);
    x = __builtin_amdgcn_update_dpp(0, __builtin_bit_cast(int, v), 0xB1, 0xf, 0xf, true);
    v += __builtin_bit_cast(float, x);
    return v;
}

// ---------- prep: per-row ||x||, exact tgt logit, xf8 in 32x32-fragment order ----------
// Byte k of a row stored at off = ((k>>3)&1)*256 + (k>>4)*8 + (k&7).
// MFMA 32x32x16 A-operand: lane l holds row (l&31), k = (l>>5)*8 + i per step.
// Lane reads its full-K set as 256 contiguous bytes at row*512 + (l>>5)*256;
// 16B at +jj*16 = steps kk=2jj,2jj+1.
__global__ __launch_bounds__(256)
void k_prep(const float* __restrict__ features,
            const float* __restrict__ W,
            const int* __restrict__ y,
            unsigned char* __restrict__ xf8,
            float* __restrict__ rowsum,
            float* __restrict__ tgt) {
    const int row = blockIdx.x;
    const int t = threadIdx.x;
    const int lane = t & 63;
    const int wave = t >> 6;
    __shared__ float redS[4], redD[4];

    const float2 v  = *(const float2*)(features + (size_t)row * DIM + t * 2);
    const float2 wv = *(const float2*)(W + (size_t)y[row] * DIM + t * 2);
    float ss = v.x * v.x + v.y * v.y;
    float dd = v.x * wv.x + v.y * wv.y;
    #pragma unroll
    for (int m = 32; m >= 1; m >>= 1) { ss += __shfl_xor(ss, m); dd += __shfl_xor(dd, m); }
    if (lane == 0) { redS[wave] = ss; redD[wave] = dd; }
    __syncthreads();
    const float tot  = redS[0] + redS[1] + redS[2] + redS[3];
    const float dtot = redD[0] + redD[1] + redD[2] + redD[3];
    const float nrm = fmaxf(sqrtf(tot), 1e-12f);
    const float sc = SEXP / nrm;

    int pk = __builtin_amdgcn_cvt_pk_fp8_f32(v.x * sc, v.y * sc, 0, false);
    const int k0 = t * 2;     // even: k0,k0+1 share (hi,kk), adjacent b
    const int off = ((k0 >> 3) & 1) * 256 + (k0 >> 4) * 8 + (k0 & 7);
    *(unsigned short*)(xf8 + (size_t)row * DIM + off) = (unsigned short)(pk & 0xFFFF);

    if (t < NRSCOPY) rowsum[t * BATCH + row] = 0.0f;
    if (t == 0) tgt[row] = dtot / nrm;
}

// ---------- fused W-convert + 32x32x16 fp8 MFMA + exp2-sum ----------
// Shape switch rationale: B streamed from LDS (allocator refuses persistent B);
// 32x32 doubles B-reuse (64 FLOP/B-byte vs 32) -> DS instrs and MFMA count
// both halve at constant FLOPs. Ws layout: class r byte k at
// r*512 + ((k>>3)&1)*256 + ((jj ^ (r&15))<<4) + (k&15-within), jj=k>>5 pair.
// Bank math (verified): stores and b128 reads both hit each bank exactly
// 8x/instruction = 1KB/instr floor, zero excess conflict.
// Epilogue: DPP red16 + 2 partial atomics per row -> DS pipe carries only B.

#define STEPJ(Af, jj) {                                                        \
    const longx2 q0_ = *(const longx2*)(&Ws[        bb + (((jj) ^ swb) << 4)]); \
    const longx2 q1_ = *(const longx2*)(&Ws[16384 + bb + (((jj) ^ swb) << 4)]); \
    acc0 = __builtin_amdgcn_mfma_f32_32x32x16_fp8_fp8(Af[jj][0], q0_[0], acc0, 0, 0, 0); \
    acc1 = __builtin_amdgcn_mfma_f32_32x32x16_fp8_fp8(Af[jj][0], q1_[0], acc1, 0, 0, 0); \
    acc0 = __builtin_amdgcn_mfma_f32_32x32x16_fp8_fp8(Af[jj][1], q0_[1], acc0, 0, 0, 0); \
    acc1 = __builtin_amdgcn_mfma_f32_32x32x16_fp8_fp8(Af[jj][1], q1_[1], acc1, 0, 0, 0); }

#define LA16(Af, c) { const unsigned char* p_ = abase + (size_t)(c) * 16384;   \
    Af[0]  = *(const longx2*)(p_ +   0); Af[1]  = *(const longx2*)(p_ +  16);  \
    Af[2]  = *(const longx2*)(p_ +  32); Af[3]  = *(const longx2*)(p_ +  48);  \
    Af[4]  = *(const longx2*)(p_ +  64); Af[5]  = *(const longx2*)(p_ +  80);  \
    Af[6]  = *(const longx2*)(p_ +  96); Af[7]  = *(const longx2*)(p_ + 112);  \
    Af[8]  = *(const longx2*)(p_ + 128); Af[9]  = *(const longx2*)(p_ + 144);  \
    Af[10] = *(const longx2*)(p_ + 160); Af[11] = *(const longx2*)(p_ + 176);  \
    Af[12] = *(const longx2*)(p_ + 192); Af[13] = *(const longx2*)(p_ + 208);  \
    Af[14] = *(const longx2*)(p_ + 224); Af[15] = *(const longx2*)(p_ + 240); }

// C/D 32x32 layout: col = lane&31, row = (reg&3) + 8*(reg>>2) + 4*(lane>>5).
// red16 gives 16-lane partials; lanes 0,16 (hi=0) and 32,48 (hi=1) each
// atomic-add their partial -> full 64-class sum lands in rowsum.
#define EPI(reg) { float p_;                                                   \
    if (full) { p_ = EXP2(acc0[reg]) + EXP2(acc1[reg]); }                      \
    else { p_ = 0.f;                                                           \
        if (n0 +      c31 < NCLS) p_ += EXP2(acc0[reg]);                       \
        if (n0 + 32 + c31 < NCLS) p_ += EXP2(acc1[reg]); }                     \
    p_ = red16(p_);                                                            \
    if ((lane & 15) == 0)                                                      \
        atomicAdd(&rs[crow_ + ((reg) & 3) + 8 * ((reg) >> 2) + 4 * hi], p_); }

#define COMPUTE(Af, c) {                                                       \
    floatx16 acc0 = {0.f,0.f,0.f,0.f,0.f,0.f,0.f,0.f,                          \
                     0.f,0.f,0.f,0.f,0.f,0.f,0.f,0.f};                         \
    floatx16 acc1 = {0.f,0.f,0.f,0.f,0.f,0.f,0.f,0.f,                          \
                     0.f,0.f,0.f,0.f,0.f,0.f,0.f,0.f};                         \
    __builtin_amdgcn_s_setprio(1);                                             \
    STEPJ(Af,0)  STEPJ(Af,1)  STEPJ(Af,2)  STEPJ(Af,3)                         \
    STEPJ(Af,4)  STEPJ(Af,5)  STEPJ(Af,6)  STEPJ(Af,7)                         \
    STEPJ(Af,8)  STEPJ(Af,9)  STEPJ(Af,10) STEPJ(Af,11)                        \
    STEPJ(Af,12) STEPJ(Af,13) STEPJ(Af,14) STEPJ(Af,15)                        \
    __builtin_amdgcn_s_setprio(0);                                             \
    const int crow_ = (wave * NCHUNK_WAVE + (c)) * CHUNK;                      \
    EPI(0)  EPI(1)  EPI(2)  EPI(3)  EPI(4)  EPI(5)  EPI(6)  EPI(7)             \
    EPI(8)  EPI(9)  EPI(10) EPI(11) EPI(12) EPI(13) EPI(14) EPI(15) }

__global__ __launch_bounds__(256, 2)
void k_gemm_fused(const float* __restrict__ W,
                  const unsigned char* __restrict__ xf8,
                  float* __restrict__ rowsum) {
    __shared__ __align__(16) unsigned char Ws[NSLAB * DIM];     // 32 KB

    const int tid  = threadIdx.x;
    const int wave = tid >> 6;
    const int lane = tid & 63;
    const int c31  = lane & 31;
    const int hi   = lane >> 5;
    const int n0   = blockIdx.x * NSLAB;
    float* rs = rowsum + (blockIdx.x & (NRSCOPY - 1)) * BATCH;

    // B-read geometry: strip s at s*16384; lane (col=c31, hi): byte
    // c31*512 + hi*256 + ((jj ^ (c31&15))<<4)
    const int bb  = c31 * 512 + hi * 256;
    const int swb = c31 & 15;

    // A base: chunk rows = (wave*8 + c)*32 + c31
    const unsigned char* abase =
        xf8 + (size_t)(wave * NCHUNK_WAVE * CHUNK + c31) * DIM + hi * 256;

    longx2 Aa[16], Ab[16];
    LA16(Aa, 0)                 // prefetch chunk 0 under Phase 1

    // ---- Phase 1: W fp32 -> fp8 e4m3 (RNE) into LDS, fragment order + swizzle.
    // Thread (r, hiw, jjw): floats [jjw*32+hiw*8, +8) (kk=2jjw) and +16 (kk odd)
    // -> 16 fp8 bytes -> one 16B store at swizzled chunk.
    #pragma unroll
    for (int j = 0; j < 8; ++j) {
        const int c   = j * 256 + tid;
        const int r   = c >> 5;          // 0..63
        const int c16 = c & 31;
        const int jjw = c16 & 15;
        const int hiw = c16 >> 4;
        int rg = n0 + r; if (rg > NCLS - 1) rg = NCLS - 1;   // tail clamp (masked later)
        const float* src = W + (size_t)rg * DIM + jjw * 32 + hiw * 8;
        const float4 e0 = *(const float4*)(src);
        const float4 e1 = *(const float4*)(src + 4);
        const float4 o0 = *(const float4*)(src + 16);
        const float4 o1 = *(const float4*)(src + 20);
        int w0 = __builtin_amdgcn_cvt_pk_fp8_f32(e0.x, e0.y, 0, false);
        w0     = __builtin_amdgcn_cvt_pk_fp8_f32(e0.z, e0.w, w0, true);
        int w1 = __builtin_amdgcn_cvt_pk_fp8_f32(e1.x, e1.y, 0, false);
        w1     = __builtin_amdgcn_cvt_pk_fp8_f32(e1.z, e1.w, w1, true);
        int w2 = __builtin_amdgcn_cvt_pk_fp8_f32(o0.x, o0.y, 0, false);
        w2     = __builtin_amdgcn_cvt_pk_fp8_f32(o0.z, o0.w, w2, true);
        int w3 = __builtin_amdgcn_cvt_pk_fp8_f32(o1.x, o1.y, 0, false);
        w3     = __builtin_amdgcn_cvt_pk_fp8_f32(o1.z, o1.w, w3, true);
        *(int4*)(&Ws[r * 512 + hiw * 256 + ((jjw ^ (r & 15)) << 4)]) =
            make_int4(w0, w1, w2, w3);
    }
    __syncthreads();

    const bool full = (n0 + NSLAB <= NCLS);

    // ---- hot loop: A dbuf from global (L2-hot), B streamed from LDS via b128
    // (2 k-steps per read), no barriers.
    #pragma unroll 1
    for (int c = 0; c < NCHUNK_WAVE; c += 2) {
        LA16(Ab, c + 1)
        COMPUTE(Aa, c)
        LA16(Aa, (c + 2) & 7)   // wrap prefetch harmless
        COMPUTE(Ab, c + 1)
    }
}

// ---------- finalize loss ----------
__global__ void k_finalize(const float* __restrict__ rowsum,
                           const float* __restrict__ tgt,
                           float* __restrict__ out) {
    const int tid = threadIdx.x;
    const int lane = tid & 63;
    const int wave = tid >> 6;
    __shared__ float red[4];

    float s = 0.f;
    #pragma unroll
    for (int i = 0; i < 4; ++i) {
        const int b = tid + i * 256;
        float rsum = 0.f;
        #pragma unroll
        for (int cp = 0; cp < NRSCOPY; ++cp) rsum += rowsum[cp * BATCH + b];
        const float traw = tgt[b];
        const float tc = fminf(fmaxf(traw, -1.0f + EPS_REF), 1.0f - EPS_REF);
        const float num = SCALE_S * cosf(acosf(tc) + MARGIN);
        const float excl = rsum - expf(SCALE_S * traw);
        const float denom = expf(num) + excl;
        s += num - logf(denom);
    }
    #pragma unroll
    for (int m = 32; m >= 1; m >>= 1) s += __shfl_xor(s, m);
    if (lane == 0) red[wave] = s;
    __syncthreads();
    if (tid == 0)
        out[0] = -(red[0] + red[1] + red[2] + red[3]) / (float)BATCH;
}

extern "C" void kernel_launch(void* const* d_in, const int* in_sizes, int n_in,
                              void* d_out, int out_size, void* d_ws, size_t ws_size,
                              hipStream_t stream) {
    const float* features = (const float*)d_in[0];
    const float* W        = (const float*)d_in[1];
    const int*   y        = (const int*)d_in[2];
    float* out = (float*)d_out;

    const size_t XF8_BYTES = (size_t)BATCH * DIM;      // 524,288
    const size_t RS_BYTES  = (size_t)NRSCOPY * BATCH * sizeof(float);   // 32 KB
    char* ws = (char*)d_ws;
    unsigned char* xf8 = (unsigned char*)ws;
    float* rowsum = (float*)(ws + XF8_BYTES);
    float* tgt    = (float*)(ws + XF8_BYTES + RS_BYTES);

    k_prep<<<BATCH, 256, 0, stream>>>(features, W, y, xf8, rowsum, tgt);
    k_gemm_fused<<<NBLK, 256, 0, stream>>>(W, xf8, rowsum);
    k_finalize<<<1, 256, 0, stream>>>(rowsum, tgt, out);
}